// Round 1
// baseline (22782.983 us; speedup 1.0000x reference)
//
#include <hip/hip_runtime.h>
#include <math.h>

// Problem constants
#define BN   128      // batch
#define TN   1440     // timesteps
#define HN   512      // hidden
#define GBn  8        // batch groups
#define BSn  16       // batches per group
#define GCn  32       // column groups
#define HCn  16       // h-cols per WG
#define NROW 48       // 3 gates * HCn rows of w_hh per WG
#define WST  520      // LDS row stride in f16 (512 + 8 pad -> 2-way-max bank conflicts on b128)

using f16 = _Float16;
typedef f16   f16x8 __attribute__((ext_vector_type(8)));
typedef float f32x4 __attribute__((ext_vector_type(4)));

// ws layout (bytes):
//   [0,1024)            flags[8][32] int
//   [1024,2048)         scal: [0]=half_tau (f32), [1]=trigger (0.0/1.0)
//   [2048,526336)       hbuf f16 [2 buf][2 plane hi/lo][128 b][512 k]
//   [526336,1263616)    xsf f32 [128][1440]
#define OFF_SCAL 1024
#define OFF_HBUF 2048
#define OFF_XSF  (2048 + 524288)

// ---------------- K0: scalar prep (grads -> half_tau, trigger) ----------------
__global__ void k_prep(const float* __restrict__ w_ih, float* __restrict__ scal) {
    __shared__ float ssum[4];
    float s = 0.0f;
    for (int i = threadIdx.x; i < 3 * HN * 2; i += 256) s += w_ih[i];
    for (int o = 32; o >= 1; o >>= 1) s += __shfl_down(s, o, 64);
    if ((threadIdx.x & 63) == 0) ssum[threadIdx.x >> 6] = s;
    __syncthreads();
    if (threadIdx.x == 0) {
        float tot = ssum[0] + ssum[1] + ssum[2] + ssum[3];
        float grads = tot / 3072.0f - 1.0f;
        float tau_new = 6.0f + grads * 0.1f;
        bool trig = (tau_new >= 1.0f) && (tau_new != 6.0f);
        scal[0] = rintf(tau_new * 0.5f);   // round-half-even matches jnp.round
        scal[1] = trig ? 1.0f : 0.0f;
    }
}

// ---------------- K1: NaN-fix + belief_fill (one wave per batch row) ----------------
__global__ void k_fill(const float* __restrict__ inp, const float* __restrict__ scal,
                       float* __restrict__ xsf) {
    const int b = blockIdx.x;
    const int lane = threadIdx.x;            // 0..63
    const float ht = scal[0];
    const bool trig = scal[1] != 0.0f;
    const float* xrow = inp + (size_t)b * 3 * TN;       // input (B,3,T,1): channel 0 = xs
    const float* mrow = xrow + 2 * TN;                   // channel 2 = mask
    const int CH = 23;                                   // 64*23 = 1472 >= 1440
    const int start = lane * CH;

    if (!trig) {
        for (int i = 0; i < CH; ++i) {
            int t = start + i;
            if (t < TN) { float x = xrow[t]; if (x != x) x = -1.0f; xsf[(size_t)b * TN + t] = x; }
        }
        return;
    }
    // forward: last observed index in my chunk
    int pm = -1;
#pragma unroll
    for (int i = 0; i < CH; ++i) { int t = start + i; if (t < TN && mrow[t] == 1.0f) pm = t; }
    int incl = pm;
    for (int o = 1; o < 64; o <<= 1) { int v = __shfl_up(incl, o, 64); if (lane >= o) incl = max(incl, v); }
    int pexcl = __shfl_up(incl, 1, 64); if (lane == 0) pexcl = -1;
    // backward: first observed index in my chunk
    int nm = TN;
#pragma unroll
    for (int i = CH - 1; i >= 0; --i) { int t = start + i; if (t < TN && mrow[t] == 1.0f) nm = t; }
    int incl2 = nm;
    for (int o = 1; o < 64; o <<= 1) { int v = __shfl_down(incl2, o, 64); if (lane + o < 64) incl2 = min(incl2, v); }
    int nexcl = __shfl_down(incl2, 1, 64); if (lane == 63) nexcl = TN;
    // per-t next-obs (descending)
    int narr[23];
    int runn = nexcl;
#pragma unroll
    for (int i = CH - 1; i >= 0; --i) {
        int t = start + i;
        if (t < TN) { if (mrow[t] == 1.0f) runn = t; narr[i] = runn; } else narr[i] = TN;
    }
    // final ascending pass: prev-obs running + emit
    int runp = pexcl;
#pragma unroll
    for (int i = 0; i < CH; ++i) {
        int t = start + i;
        if (t >= TN) break;
        float x = xrow[t]; if (x != x) x = -1.0f;
        if (mrow[t] == 1.0f) runp = t;
        int pv = runp, nv = narr[i];
        int pc = min(max(pv, 0), TN - 1), nc = min(max(nv, 0), TN - 1);
        float xp = xrow[pc]; if (xp != xp) xp = -1.0f;
        float xn = xrow[nc]; if (xn != xn) xn = -1.0f;
        bool use_n = (nv < TN) && ((float)t >= (float)nv - ht);
        bool use_p = (pv >= 0) && ((float)t <= (float)pv + ht);
        float o = use_n ? xn : (use_p ? xp : x);
        xsf[(size_t)b * TN + t] = o;
    }
}

// ---------------- K2: persistent column-split GRU ----------------
// grid 256 = 8 batch-groups x 32 col-groups; block 256 (4 waves); 1 WG/CU (LDS ~134 KB).
// WG (gb,gc): owns h cols [gc*16, gc*16+16), gate rows {g*512 + gc*16 + j}. Weights f16 hi/lo
// in LDS forever. Per step: poll 32 peer flags, acquire, stage h_t (hi/lo) to LDS, 3 waves do
// MFMA (gate r/z/n tiles, 16 k-chunks x 3 split terms), gate math in fp32, publish h_{t+1}
// slice + release flag. Double-buffered h in ws; flags are step counters (memset 0 each launch).
__global__ __launch_bounds__(256, 1) void k_gru(
    const float* __restrict__ inp, const float* __restrict__ w_ih,
    const float* __restrict__ w_hh, const float* __restrict__ b_ih,
    const float* __restrict__ b_hh, const float* __restrict__ w_fc,
    const float* __restrict__ b_fc, const float* __restrict__ xsf,
    f16* __restrict__ hbuf, int* __restrict__ flags, float* __restrict__ out) {
    __shared__ __align__(16) f16 sWhi[NROW * WST];
    __shared__ __align__(16) f16 sWlo[NROW * WST];
    __shared__ __align__(16) f16 sHhi[BSn * WST];
    __shared__ __align__(16) f16 sHlo[BSn * WST];
    __shared__ float sGh[3][BSn][HCn + 1];
    __shared__ float sWi0[NROW], sWi1[NROW], sBias[NROW];

    const int tid = threadIdx.x;
    const int gb = blockIdx.x & 7;    // blockIdx%8 -> same-XCD heuristic for a batch group
    const int gc = blockIdx.x >> 3;   // 0..31

    // --- one-time: stage weight slice as f16 hi + (lo * 2^11) ---
    for (int i = tid; i < NROW * HN; i += 256) {
        int row = i >> 9, col = i & 511;
        int gate = row >> 4, jj = row & 15;
        int grow = gate * HN + gc * HCn + jj;
        float w = w_hh[grow * HN + col];
        f16 hi = (f16)w;
        f16 lo = (f16)((w - (float)hi) * 2048.0f);
        sWhi[row * WST + col] = hi;
        sWlo[row * WST + col] = lo;
    }
    if (tid < NROW) {
        int gate = tid >> 4, jj = tid & 15;
        int grow = gate * HN + gc * HCn + jj;
        sWi0[tid]  = w_ih[grow * 2 + 0];
        sWi1[tid]  = w_ih[grow * 2 + 1];
        sBias[tid] = b_ih[grow] + b_hh[grow];
    }
    __syncthreads();

    const int lane = tid & 63;
    const int wv   = tid >> 6;
    const int bs   = tid >> 4;        // gate-math mapping: (bs, j)
    const int j    = tid & 15;
    const int bglob = gb * BSn + bs;
    const int pcol  = gc * HCn + j;
    const int frow = lane & 15;       // MFMA m (A) / n (B) index
    const int kgrp = lane >> 4;       // MFMA k-group
    const int wvc = (wv < 3) ? wv : 2;
    const f16x8* pAhi = (const f16x8*)(sHhi + frow * WST);
    const f16x8* pAlo = (const f16x8*)(sHlo + frow * WST);
    const f16x8* pBhi = (const f16x8*)(sWhi + (wvc * 16 + frow) * WST);
    const f16x8* pBlo = (const f16x8*)(sWlo + (wvc * 16 + frow) * WST);
    int* myflags = flags + gb * GCn;
    float h = 0.0f;

    for (int t = 0; t < TN; ++t) {
        // prefetch driving inputs (independent of sync)
        float xsv = xsf[(size_t)bglob * TN + t];
        float mkv = inp[((size_t)bglob * 3 + 2) * TN + t];
        // 1. wait: all 32 peer slices of h_t published
        if (wv == 0 && lane < GCn) {
            while (__hip_atomic_load(&myflags[lane], __ATOMIC_RELAXED, __HIP_MEMORY_SCOPE_AGENT) < t)
                __builtin_amdgcn_s_sleep(1);
        }
        __syncthreads();
        __builtin_amdgcn_fence(__ATOMIC_ACQUIRE, "agent");
        // 2. stage h_t (hi/lo planes) into LDS, [bs][k] rows
        {
            const int buf = t & 1;
            const f16* srcHi = hbuf + ((size_t)((buf << 1) + 0) * BN + gb * BSn) * HN;
            const f16* srcLo = hbuf + ((size_t)((buf << 1) + 1) * BN + gb * BSn) * HN;
#pragma unroll
            for (int q = 0; q < 4; ++q) {
                int c = q * 256 + tid;               // 0..1023 chunks of 8 f16
                int brow = c >> 6, koff = (c & 63) << 3;
                uint4 vhi = *(const uint4*)(srcHi + brow * HN + koff);
                uint4 vlo = *(const uint4*)(srcLo + brow * HN + koff);
                *(uint4*)(sHhi + brow * WST + koff) = vhi;
                *(uint4*)(sHlo + brow * WST + koff) = vlo;
            }
        }
        __syncthreads();
        // 3. MFMA: wave wv computes gate tile wv (16x16), K=512, 3 split terms
        if (wv < 3) {
            f32x4 acch = {0.f, 0.f, 0.f, 0.f}, accl = {0.f, 0.f, 0.f, 0.f};
#pragma unroll
            for (int c = 0; c < 16; ++c) {
                f16x8 ah = pAhi[c * 4 + kgrp];
                f16x8 al = pAlo[c * 4 + kgrp];
                f16x8 bh = pBhi[c * 4 + kgrp];
                f16x8 bl = pBlo[c * 4 + kgrp];
                acch = __builtin_amdgcn_mfma_f32_16x16x32_f16(ah, bh, acch, 0, 0, 0);
                accl = __builtin_amdgcn_mfma_f32_16x16x32_f16(ah, bl, accl, 0, 0, 0);
                accl = __builtin_amdgcn_mfma_f32_16x16x32_f16(al, bh, accl, 0, 0, 0);
            }
            // C/D: row=(lane>>4)*4+r (batch), col=lane&15 (j)
#pragma unroll
            for (int r = 0; r < 4; ++r)
                sGh[wv][kgrp * 4 + r][frow] = acch[r] + accl[r] * (1.0f / 2048.0f);
        }
        __syncthreads();
        // 4. exact fp32 gate math + publish h_{t+1} slice
        {
            float ghr = sGh[0][bs][j], ghz = sGh[1][bs][j], ghn = sGh[2][bs][j];
            float gir = xsv * sWi0[j]      + mkv * sWi1[j]      + sBias[j];
            float giz = xsv * sWi0[16 + j] + mkv * sWi1[16 + j] + sBias[16 + j];
            float gin = xsv * sWi0[32 + j] + mkv * sWi1[32 + j] + sBias[32 + j];
            float rg = 1.0f / (1.0f + __expf(-(gir + ghr)));
            float zg = 1.0f / (1.0f + __expf(-(giz + ghz)));
            float ng = tanhf(gin + rg * ghn);
            h = (1.0f - zg) * ng + zg * h;
            f16 hi = (f16)h;
            f16 lo = (f16)((h - (float)hi) * 2048.0f);
            const int nbuf = (t + 1) & 1;
            hbuf[((size_t)((nbuf << 1) + 0) * BN + bglob) * HN + pcol] = hi;
            hbuf[((size_t)((nbuf << 1) + 1) * BN + bglob) * HN + pcol] = lo;
        }
        __syncthreads();   // compiler drains vmcnt before s_barrier -> stores L2-visible
        if (tid == 0)
            __hip_atomic_store(&myflags[gc], t + 1, __ATOMIC_RELEASE, __HIP_MEMORY_SCOPE_AGENT);
    }
    // 5. final FC: out[b] = sum_k h[b][k]*w_fc[k] + b_fc
    float part = h * w_fc[pcol];
    for (int o = 1; o < 16; o <<= 1) part += __shfl_xor(part, o, 64);
    if (j == 0) {
        if (gc == 0) part += b_fc[0];
        atomicAdd(&out[bglob], part);
    }
}

extern "C" void kernel_launch(void* const* d_in, const int* in_sizes, int n_in,
                              void* d_out, int out_size, void* d_ws, size_t ws_size,
                              hipStream_t stream) {
    const float* inp  = (const float*)d_in[0];
    const float* w_ih = (const float*)d_in[1];
    const float* w_hh = (const float*)d_in[2];
    const float* b_ih = (const float*)d_in[3];
    const float* b_hh = (const float*)d_in[4];
    const float* w_fc = (const float*)d_in[5];
    const float* b_fc = (const float*)d_in[6];
    float* out = (float*)d_out;
    char* ws = (char*)d_ws;
    int*   flags = (int*)ws;
    float* scal  = (float*)(ws + OFF_SCAL);
    f16*   hbuf  = (f16*)(ws + OFF_HBUF);
    float* xsf   = (float*)(ws + OFF_XSF);

    // zero: flags + scal + h double-buffer's buf0 (= h_0 = 0); d_out (atomicAdd target)
    hipMemsetAsync(ws, 0, OFF_HBUF + 2 * BN * HN * sizeof(f16), stream);
    hipMemsetAsync(d_out, 0, BN * sizeof(float), stream);
    k_prep<<<1, 256, 0, stream>>>(w_ih, scal);
    k_fill<<<BN, 64, 0, stream>>>(inp, scal, xsf);
    k_gru<<<GBn * GCn, 256, 0, stream>>>(inp, w_ih, w_hh, b_ih, b_hh, w_fc, b_fc,
                                         xsf, hbuf, flags, out);
}

// Round 2
// 3975.431 us; speedup vs baseline: 5.7309x; 5.7309x over previous
//
#include <hip/hip_runtime.h>
#include <math.h>

// Problem constants
#define BN   128      // batch
#define TN   1440     // timesteps
#define HN   512      // hidden
#define GBn  8        // batch groups
#define BSn  16       // batches per group
#define GCn  32       // column groups
#define HCn  16       // h-cols per WG
#define WST  536      // LDS row stride in f16: 268 dw == 12 mod 32 -> conflict-free b128 frag reads

using f16 = _Float16;
typedef f16   f16x8 __attribute__((ext_vector_type(8)));
typedef float f32x4 __attribute__((ext_vector_type(4)));
typedef unsigned int       uint32;
typedef unsigned long long u64;

// ws layout (bytes):
//   [0,1024)             flags[8][32] int
//   [1024,2048)          scal: [0]=half_tau, [1]=trigger
//   [2048,526336)        hbufP uint32 [2 buf][128 b][512 k]  (packed: lo16=f16 hi, hi16=f16 lo*2048)
//   [526336,1263616)     xsf f32 [128][1440]
#define OFF_SCAL 1024
#define OFF_HBUF 2048
#define OFF_XSF  (2048 + 2 * BN * HN * 4)

// ---------------- K0: scalar prep (grads -> half_tau, trigger) ----------------
__global__ void k_prep(const float* __restrict__ w_ih, float* __restrict__ scal) {
    __shared__ float ssum[4];
    float s = 0.0f;
    for (int i = threadIdx.x; i < 3 * HN * 2; i += 256) s += w_ih[i];
    for (int o = 32; o >= 1; o >>= 1) s += __shfl_down(s, o, 64);
    if ((threadIdx.x & 63) == 0) ssum[threadIdx.x >> 6] = s;
    __syncthreads();
    if (threadIdx.x == 0) {
        float tot = ssum[0] + ssum[1] + ssum[2] + ssum[3];
        float grads = tot / 3072.0f - 1.0f;
        float tau_new = 6.0f + grads * 0.1f;
        bool trig = (tau_new >= 1.0f) && (tau_new != 6.0f);
        scal[0] = rintf(tau_new * 0.5f);   // round-half-even matches jnp.round
        scal[1] = trig ? 1.0f : 0.0f;
    }
}

// ---------------- K1: NaN-fix + belief_fill (one wave per batch row) ----------------
__global__ void k_fill(const float* __restrict__ inp, const float* __restrict__ scal,
                       float* __restrict__ xsf) {
    const int b = blockIdx.x;
    const int lane = threadIdx.x;            // 0..63
    const float ht = scal[0];
    const bool trig = scal[1] != 0.0f;
    const float* xrow = inp + (size_t)b * 3 * TN;       // channel 0 = xs
    const float* mrow = xrow + 2 * TN;                   // channel 2 = mask
    const int CH = 23;                                   // 64*23 = 1472 >= 1440
    const int start = lane * CH;

    if (!trig) {
        for (int i = 0; i < CH; ++i) {
            int t = start + i;
            if (t < TN) { float x = xrow[t]; if (x != x) x = -1.0f; xsf[(size_t)b * TN + t] = x; }
        }
        return;
    }
    int pm = -1;
#pragma unroll
    for (int i = 0; i < CH; ++i) { int t = start + i; if (t < TN && mrow[t] == 1.0f) pm = t; }
    int incl = pm;
    for (int o = 1; o < 64; o <<= 1) { int v = __shfl_up(incl, o, 64); if (lane >= o) incl = max(incl, v); }
    int pexcl = __shfl_up(incl, 1, 64); if (lane == 0) pexcl = -1;
    int nm = TN;
#pragma unroll
    for (int i = CH - 1; i >= 0; --i) { int t = start + i; if (t < TN && mrow[t] == 1.0f) nm = t; }
    int incl2 = nm;
    for (int o = 1; o < 64; o <<= 1) { int v = __shfl_down(incl2, o, 64); if (lane + o < 64) incl2 = min(incl2, v); }
    int nexcl = __shfl_down(incl2, 1, 64); if (lane == 63) nexcl = TN;
    int narr[23];
    int runn = nexcl;
#pragma unroll
    for (int i = CH - 1; i >= 0; --i) {
        int t = start + i;
        if (t < TN) { if (mrow[t] == 1.0f) runn = t; narr[i] = runn; } else narr[i] = TN;
    }
    int runp = pexcl;
#pragma unroll
    for (int i = 0; i < CH; ++i) {
        int t = start + i;
        if (t >= TN) break;
        float x = xrow[t]; if (x != x) x = -1.0f;
        if (mrow[t] == 1.0f) runp = t;
        int pv = runp, nv = narr[i];
        int pc = min(max(pv, 0), TN - 1), nc = min(max(nv, 0), TN - 1);
        float xp = xrow[pc]; if (xp != xp) xp = -1.0f;
        float xn = xrow[nc]; if (xn != xn) xn = -1.0f;
        bool use_n = (nv < TN) && ((float)t >= (float)nv - ht);
        bool use_p = (pv >= 0) && ((float)t <= (float)pv + ht);
        float o = use_n ? xn : (use_p ? xp : x);
        xsf[(size_t)b * TN + t] = o;
    }
}

// ---------------- K2: persistent column-split GRU, L3-coherent comm ----------------
// grid 256 = 8 batch-groups x 32 col-groups; block 256 (4 waves); 1 WG/CU.
// Communication: relaxed agent-scope atomics only (global_* sc0 sc1 -> write-through /
// read-past L2, coherent at L3). NO acquire/release fences -> no buffer_wbl2/buffer_inv.
// Producer ordering: __syncthreads drains vmcnt(0) (store ack at coherence point) before
// the tid0 flag store. XCD-assignment independent (G16-safe).
// Weights: B-fragments (f16 hi + lo*2^11) resident in VGPRs for the whole t-loop.
__global__ __launch_bounds__(256, 1) void k_gru(
    const float* __restrict__ inp, const float* __restrict__ w_ih,
    const float* __restrict__ w_hh, const float* __restrict__ b_ih,
    const float* __restrict__ b_hh, const float* __restrict__ w_fc,
    const float* __restrict__ b_fc, const float* __restrict__ xsf,
    uint32* __restrict__ hbufP, int* __restrict__ flags, float* __restrict__ out) {
    __shared__ __align__(16) f16 sHhi[BSn * WST];
    __shared__ __align__(16) f16 sHlo[BSn * WST];
    __shared__ float sGh[3][BSn][HCn + 1];
    __shared__ float sWi0[48], sWi1[48], sBias[48];

    const int tid = threadIdx.x;
    const int gb = blockIdx.x & 7;
    const int gc = blockIdx.x >> 3;
    const int lane = tid & 63;
    const int wv   = tid >> 6;
    const int bs   = tid >> 4;        // gate-math row 0..15
    const int j    = tid & 15;
    const int bglob = gb * BSn + bs;
    const int pcol  = gc * HCn + j;
    const int frow = lane & 15;       // MFMA m (A) / n (B) index
    const int kgrp = lane >> 4;       // MFMA k-group

    if (tid < 48) {
        int gate = tid >> 4, jj = tid & 15;
        int grow = gate * HN + gc * HCn + jj;
        sWi0[tid]  = w_ih[grow * 2 + 0];
        sWi1[tid]  = w_ih[grow * 2 + 1];
        sBias[tid] = b_ih[grow] + b_hh[grow];
    }

    // one-time: weight B-fragments into VGPRs (hi + lo*2^11 split)
    f16x8 bfh[16], bfl[16];
    if (wv < 3) {
        const float* wrow = w_hh + (size_t)(wv * HN + gc * HCn + frow) * HN;
#pragma unroll
        for (int c = 0; c < 16; ++c) {
            const int k0 = (c * 4 + kgrp) * 8;
#pragma unroll
            for (int u = 0; u < 8; ++u) {
                float w = wrow[k0 + u];
                f16 hi = (f16)w;
                bfh[c][u] = hi;
                bfl[c][u] = (f16)((w - (float)hi) * 2048.0f);
            }
        }
    }
    __syncthreads();

    int* myflags = flags + gb * GCn;
    const f16x8* pAhi = (const f16x8*)(sHhi + frow * WST);
    const f16x8* pAlo = (const f16x8*)(sHlo + frow * WST);
    float h = 0.0f;

    for (int t = 0; t < TN; ++t) {
        // prefetch driving inputs (independent of sync)
        float xsv = xsf[(size_t)bglob * TN + t];
        float mkv = inp[((size_t)bglob * 3 + 2) * TN + t];
        // 1. every wave polls all 32 peer flags (relaxed atomic load = L3 read, no inv)
        if (lane < GCn) {
            while (__hip_atomic_load(&myflags[lane], __ATOMIC_RELAXED, __HIP_MEMORY_SCOPE_AGENT) < t) {}
        }
        // 2. stage h_t into LDS: 16 coherent u64 loads/thread (2 packed dwords of batch row i)
        {
            const uint32* src = hbufP + ((size_t)(t & 1) * BN + gb * BSn) * HN;
            u64 hv[16];
#pragma unroll
            for (int i = 0; i < 16; ++i)
                hv[i] = __hip_atomic_load((const u64*)(src + (size_t)i * HN) + tid,
                                          __ATOMIC_RELAXED, __HIP_MEMORY_SCOPE_AGENT);
#pragma unroll
            for (int i = 0; i < 16; ++i) {
                uint32 d0 = (uint32)hv[i], d1 = (uint32)(hv[i] >> 32);
                ((uint32*)(sHhi + i * WST))[tid] = __builtin_amdgcn_perm(d1, d0, 0x05040100u);
                ((uint32*)(sHlo + i * WST))[tid] = __builtin_amdgcn_perm(d1, d0, 0x07060302u);
            }
        }
        __syncthreads();
        // 3. MFMA: wave wv computes gate tile wv (16x16), K=512, 3 split terms
        if (wv < 3) {
            f32x4 acch = {0.f, 0.f, 0.f, 0.f}, accl = {0.f, 0.f, 0.f, 0.f};
#pragma unroll
            for (int c = 0; c < 16; ++c) {
                f16x8 ah = pAhi[c * 4 + kgrp];
                f16x8 al = pAlo[c * 4 + kgrp];
                acch = __builtin_amdgcn_mfma_f32_16x16x32_f16(ah, bfh[c], acch, 0, 0, 0);
                accl = __builtin_amdgcn_mfma_f32_16x16x32_f16(ah, bfl[c], accl, 0, 0, 0);
                accl = __builtin_amdgcn_mfma_f32_16x16x32_f16(al, bfh[c], accl, 0, 0, 0);
            }
            // C/D: row=(lane>>4)*4+r (batch), col=lane&15 (j)
#pragma unroll
            for (int r = 0; r < 4; ++r)
                sGh[wv][kgrp * 4 + r][frow] = acch[r] + accl[r] * (1.0f / 2048.0f);
        }
        __syncthreads();
        // 4. exact fp32 gate math + publish h_{t+1} slice (write-through atomic store)
        {
            float ghr = sGh[0][bs][j], ghz = sGh[1][bs][j], ghn = sGh[2][bs][j];
            float gir = xsv * sWi0[j]      + mkv * sWi1[j]      + sBias[j];
            float giz = xsv * sWi0[16 + j] + mkv * sWi1[16 + j] + sBias[16 + j];
            float gin = xsv * sWi0[32 + j] + mkv * sWi1[32 + j] + sBias[32 + j];
            float rg = 1.0f / (1.0f + __expf(-(gir + ghr)));
            float zg = 1.0f / (1.0f + __expf(-(giz + ghz)));
            float ng = tanhf(gin + rg * ghn);
            h = (1.0f - zg) * ng + zg * h;
            f16 hi = (f16)h;
            f16 lo = (f16)((h - (float)hi) * 2048.0f);
            uint32 pk = (uint32)__builtin_bit_cast(unsigned short, hi)
                      | ((uint32)__builtin_bit_cast(unsigned short, lo) << 16);
            __hip_atomic_store(&hbufP[((size_t)((t + 1) & 1) * BN + bglob) * HN + pcol], pk,
                               __ATOMIC_RELAXED, __HIP_MEMORY_SCOPE_AGENT);
        }
        __syncthreads();   // compiler drains vmcnt(0) before s_barrier -> publishes acked at L3
        if (tid == 0)
            __hip_atomic_store(&myflags[gc], t + 1, __ATOMIC_RELAXED, __HIP_MEMORY_SCOPE_AGENT);
    }
    // 5. final FC: out[b] = sum_k h[b][k]*w_fc[k] + b_fc
    float part = h * w_fc[pcol];
#pragma unroll
    for (int o = 1; o < 16; o <<= 1) part += __shfl_xor(part, o, 64);
    if (j == 0) {
        if (gc == 0) part += b_fc[0];
        atomicAdd(&out[bglob], part);
    }
}

extern "C" void kernel_launch(void* const* d_in, const int* in_sizes, int n_in,
                              void* d_out, int out_size, void* d_ws, size_t ws_size,
                              hipStream_t stream) {
    const float* inp  = (const float*)d_in[0];
    const float* w_ih = (const float*)d_in[1];
    const float* w_hh = (const float*)d_in[2];
    const float* b_ih = (const float*)d_in[3];
    const float* b_hh = (const float*)d_in[4];
    const float* w_fc = (const float*)d_in[5];
    const float* b_fc = (const float*)d_in[6];
    float* out = (float*)d_out;
    char* ws = (char*)d_ws;
    int*    flags = (int*)ws;
    float*  scal  = (float*)(ws + OFF_SCAL);
    uint32* hbufP = (uint32*)(ws + OFF_HBUF);
    float*  xsf   = (float*)(ws + OFF_XSF);

    // zero: flags + scal + packed-h buf0 (= h_0 = 0); d_out (atomicAdd target)
    hipMemsetAsync(ws, 0, OFF_HBUF + BN * HN * 4, stream);
    hipMemsetAsync(d_out, 0, BN * sizeof(float), stream);
    k_prep<<<1, 256, 0, stream>>>(w_ih, scal);
    k_fill<<<BN, 64, 0, stream>>>(inp, scal, xsf);
    k_gru<<<GBn * GCn, 256, 0, stream>>>(inp, w_ih, w_hh, b_ih, b_hh, w_fc, b_fc,
                                         xsf, hbufP, flags, out);
}